// Round 10
// baseline (103.268 us; speedup 1.0000x reference)
//
#include <hip/hip_runtime.h>
#include <hip/hip_fp16.h>
#include <stdint.h>

#define HH   56
#define WW   56
#define HWP  3136
#define CC   256
#define GG   16
#define CGR  16
#define KT   7
#define KK   49
#define RCP  32            // packed f16 channel-pairs (64 ch)
#define TH   4             // rows per invol block
#define NPX  (TH * WW)     // 224 px per block
#define XROW 36            // u32 per sXh row (64 f16 used + pad)
#define XPL  364           // u32 per sXh ch-plane (10*36+4)
#define BQ4  (NPX * 4)     // ldsB pitch per q4 (u32)

typedef _Float16 h2_t   __attribute__((ext_vector_type(2)));
typedef __fp16   fp16x2 __attribute__((ext_vector_type(2)));
typedef _Float16 v8h    __attribute__((ext_vector_type(8)));
typedef float    v4f    __attribute__((ext_vector_type(4)));
union pk32 { uint32_t u; h2_t h; __half2 hh; fp16x2 f; };
union frag { uint32_t u[4]; v8h h; };

static __device__ __forceinline__ uint32_t pkrtz(float a, float b) {
    pk32 p; p.f = __builtin_amdgcn_cvt_pkrtz(a, b); return p.u;
}

// pack a 32-channel f32 row-segment into an 8xf16-pair MFMA A-half-fragment
static __device__ __forceinline__ frag pack_afrag(const float* rowp, int quad) {
    frag a;
    const float4 p0 = *(const float4*)&rowp[quad * 8];
    const float4 p1 = *(const float4*)&rowp[quad * 8 + 4];
    a.u[0] = pkrtz(p0.x, p0.y); a.u[1] = pkrtz(p0.z, p0.w);
    a.u[2] = pkrtz(p1.x, p1.y); a.u[3] = pkrtz(p1.z, p1.w);
    return a;
}

// ---- gemm1 via MFMA: h2[b][cpair][px] = pack_f16 pairs of rw@x + rb --------
// px-tile 16, grid (196,1,4) = 784 blocks (3 blocks/CU); K=256 prefetched.
__global__ __launch_bounds__(256)
void gemm1_mfma(const float* __restrict__ rw, const float* __restrict__ rb,
                const float* __restrict__ x, uint32_t* __restrict__ h2)
{
    const int b = blockIdx.z, px0 = blockIdx.x * 16;
    const int t = threadIdx.x;
    const int wave = t >> 6, lane = t & 63, quad = lane >> 4, n16 = lane & 15;

    __shared__ __align__(16) uint32_t ldsB[2][512];   // [buf][q4*64+px*4+jj], 4 KB

    const int px = t & 15;          // staging: 16 px x 16 cp (c2 = cp and cp+16)
    const int cp = t >> 4;
    const float* xb = x + (size_t)b * CC * HWP + px0 + px;

    float ra[4][4];                 // all 4 K-chunks prefetched
#pragma unroll
    for (int k = 0; k < 4; ++k) {
        ra[k][0] = xb[(size_t)(k * 64 + 2 * cp) * HWP];
        ra[k][1] = xb[(size_t)(k * 64 + 2 * cp + 1) * HWP];
        ra[k][2] = xb[(size_t)(k * 64 + 2 * cp + 32) * HWP];
        ra[k][3] = xb[(size_t)(k * 64 + 2 * cp + 33) * HWP];
    }
    const int q4a = cp >> 2, jja = cp & 3;
    ldsB[0][q4a * 64 + px * 4 + jja]       = pkrtz(ra[0][0], ra[0][1]);
    ldsB[0][(q4a + 4) * 64 + px * 4 + jja] = pkrtz(ra[0][2], ra[0][3]);
    __syncthreads();

    const float* rwr = rw + (size_t)(wave * 16 + n16) * CC;
    v4f acc = v4f{0.f, 0.f, 0.f, 0.f};
#pragma unroll
    for (int k = 0; k < 4; ++k) {
        if (k < 3) {
            ldsB[(k + 1) & 1][q4a * 64 + px * 4 + jja]       = pkrtz(ra[k+1][0], ra[k+1][1]);
            ldsB[(k + 1) & 1][(q4a + 4) * 64 + px * 4 + jja] = pkrtz(ra[k+1][2], ra[k+1][3]);
        }
        const frag a0 = pack_afrag(rwr + k * 64, quad);
        const frag a1 = pack_afrag(rwr + k * 64 + 32, quad);
        frag b0, b1;
        *(uint4*)b0.u = *(const uint4*)&ldsB[k & 1][quad * 64 + n16 * 4];
        *(uint4*)b1.u = *(const uint4*)&ldsB[k & 1][(4 + quad) * 64 + n16 * 4];
        acc = __builtin_amdgcn_mfma_f32_16x16x32_f16(a0.h, b0.h, acc, 0, 0, 0);
        acc = __builtin_amdgcn_mfma_f32_16x16x32_f16(a1.h, b1.h, acc, 0, 0, 0);
        if (k < 3) __syncthreads();
    }
    uint32_t* hb = h2 + (size_t)b * RCP * HWP + px0;
#pragma unroll
    for (int pr = 0; pr < 2; ++pr) {
        const int m0 = wave * 16 + quad * 4 + 2 * pr;
        hb[(size_t)(wave * 8 + quad * 2 + pr) * HWP + n16] =
            pkrtz(acc[2 * pr] + rb[m0], acc[2 * pr + 1] + rb[m0 + 1]);
    }
}

// ---- fused MFMA kern-gen + pk-f16 involution (TH=4, 2ch/thread phase C) ----
// LDS: sXh 22.75 KB + U 28 KB (ldsB, overlaid with sK f16) = 50.75 KB -> 3 blocks/CU
__global__ __launch_bounds__(256, 3)
void invol_fused(const float* __restrict__ x, const uint32_t* __restrict__ h2,
                 const float* __restrict__ sw, const float* __restrict__ sb,
                 float* __restrict__ out)
{
    const int h0 = blockIdx.x * TH, g = blockIdx.y, b = blockIdx.z;

    __shared__ __align__(16) uint32_t sXh[16 * XPL];   // f16 x, [ch][row][64f16]
    __shared__ __align__(16) uint32_t U[8 * BQ4];      // ldsB [q4][px*4+jj]; later sK f16 [tap*NPX+px]

    const int t = threadIdx.x;
    const int wave = t >> 6, lane = t & 63, quad = lane >> 4, n16 = lane & 15;

    // A-frags: pack from f32 sw (wave-uniform row block, L2/L3-hot)
    const int mt0 = wave * 16 + n16;
    const int mtap = mt0 > 48 ? 48 : mt0;
    const float* swr = sw + (size_t)(g * KK + mtap) * 64;
    const frag a0 = pack_afrag(swr, quad);
    const frag a1 = pack_afrag(swr + 32, quad);

    float bvv[4];
#pragma unroll
    for (int reg = 0; reg < 4; ++reg) {
        const int tp = wave * 16 + quad * 4 + reg;
        bvv[reg] = (tp < KK) ? sb[g * KK + tp] : 0.f;
    }

    // stage h2 -> ldsB in B-frag order (4-channel gather -> one b128 write)
    {
        const uint32_t* hb = h2 + (size_t)b * RCP * HWP + h0 * WW;
#pragma unroll
        for (int k = 0; k < 7; ++k) {               // 1792 slots exact
            const int i = t + 256 * k;
            const int px = i % NPX, q4 = i / NPX;
            uint4 w;
            w.x = hb[(size_t)(q4 * 4 + 0) * HWP + px];
            w.y = hb[(size_t)(q4 * 4 + 1) * HWP + px];
            w.z = hb[(size_t)(q4 * 4 + 2) * HWP + px];
            w.w = hb[(size_t)(q4 * 4 + 3) * HWP + px];
            *(uint4*)&U[q4 * BQ4 + px * 4] = w;
        }
    }

    // halo zero: f16 cols 0..3 / 60..63 per (ch,row): 320 b64 slots
#pragma unroll
    for (int k = 0; k < 2; ++k) {
        const int i = t + 256 * k;
        if (i < 320) {
            const int ch = i / 20, rem = i % 20, rr = rem >> 1, side = rem & 1;
            uint2 z; z.x = 0; z.y = 0;
            *(uint2*)&sXh[ch * XPL + rr * XROW + (side ? 30 : 0)] = z;
        }
    }

    // x interior -> f16 (10 rows incl. halo; invalid rows write zero): 2240 slots
    {
        const float* xb = x + (size_t)(b * CC + g * CGR) * HWP;
#pragma unroll
        for (int k = 0; k < 9; ++k) {
            const int i = t + 256 * k;
            if (i < 2240) {
                const int w4 = i % 14, rr = (i / 14) % 10, ch = i / 140;
                const int hh = h0 - 3 + rr;
                float4 v = make_float4(0.f, 0.f, 0.f, 0.f);
                if (hh >= 0 && hh < HH)
                    v = *(const float4*)&xb[(size_t)ch * HWP + hh * WW + 4 * w4];
                uint2 p; p.x = pkrtz(v.x, v.y); p.y = pkrtz(v.z, v.w);
                *(uint2*)&sXh[ch * XPL + rr * XROW + 2 + 2 * w4] = p;
            }
        }
    }
    __syncthreads();                                // barrier 1

    // MFMA: K[49][224] = SW[49][64] @ H[64][224]; 14 n-tiles x 2 k-chunks
    v4f acc[14];
#pragma unroll
    for (int nt = 0; nt < 14; ++nt) acc[nt] = v4f{0.f, 0.f, 0.f, 0.f};
#pragma unroll
    for (int nt = 0; nt < 14; ++nt) {
        const int pxm = (nt * 16 + n16) * 4;
        frag b0, b1;
        *(uint4*)b0.u = *(const uint4*)&U[quad * BQ4 + pxm];
        *(uint4*)b1.u = *(const uint4*)&U[(4 + quad) * BQ4 + pxm];
        acc[nt] = __builtin_amdgcn_mfma_f32_16x16x32_f16(a0.h, b0.h, acc[nt], 0, 0, 0);
        acc[nt] = __builtin_amdgcn_mfma_f32_16x16x32_f16(a1.h, b1.h, acc[nt], 0, 0, 0);
    }
    __syncthreads();                                // barrier 2: ldsB dead

    // epilogue -> sK f16 [tap][NPX]
    {
        _Float16* sK = (_Float16*)U;
#pragma unroll
        for (int nt = 0; nt < 14; ++nt) {
            const int px = nt * 16 + n16;
#pragma unroll
            for (int reg = 0; reg < 4; ++reg) {
                const int tp = wave * 16 + quad * 4 + reg;
                if (tp < KK) sK[tp * NPX + px] = (_Float16)(acc[nt][reg] + bvv[reg]);
            }
        }
    }
    __syncthreads();                                // barrier 3

    // phase C: thread = (chq pair, r, wq); 2 ch x 8 px outputs
    if (t < 224) {
        const int chq = t & 7, q = t >> 3;
        const int r = q / 7, wq = q % 7;
        const int ch0 = 2 * chq;
        const uint32_t* xp0 = &sXh[ch0 * XPL + 4 * wq];
        const uint32_t* xp1 = &sXh[(ch0 + 1) * XPL + 4 * wq];
        float oa[2][8];
#pragma unroll
        for (int c = 0; c < 2; ++c)
#pragma unroll
            for (int j = 0; j < 8; ++j) oa[c][j] = 0.f;

#pragma unroll
        for (int kh = 0; kh < KT; ++kh) {
            const int rr = r + kh;
            uint32_t E0[8], E1[8], O0[7], O1[7];
            *(uint4*)&E0[0] = *(const uint4*)&xp0[rr * XROW];
            *(uint4*)&E0[4] = *(const uint4*)&xp0[rr * XROW + 4];
            *(uint4*)&E1[0] = *(const uint4*)&xp1[rr * XROW];
            *(uint4*)&E1[4] = *(const uint4*)&xp1[rr * XROW + 4];
#pragma unroll
            for (int j = 0; j < 7; ++j) {
                O0[j] = __builtin_amdgcn_alignbit(E0[j + 1], E0[j], 16);
                O1[j] = __builtin_amdgcn_alignbit(E1[j + 1], E1[j], 16);
            }
            pk32 va[2][4];
#pragma unroll
            for (int c = 0; c < 2; ++c)
#pragma unroll
                for (int j = 0; j < 4; ++j) va[c][j].u = 0;

            const uint32_t* kq = &U[(kh * KT) * (NPX / 2) + r * 28 + 4 * wq];
#pragma unroll
            for (int kw = 0; kw < KT; ++kw) {
                const uint4 kk = *(const uint4*)&kq[kw * (NPX / 2)];
                pk32 k0, k1, k2, k3; k0.u = kk.x; k1.u = kk.y; k2.u = kk.z; k3.u = kk.w;
                uint32_t s0, s1, s2, s3, u0, u1, u2, u3;
                if (kw & 1) {
                    const int e = (kw + 1) >> 1;
                    s0 = E0[e]; s1 = E0[e + 1]; s2 = E0[e + 2]; s3 = E0[e + 3];
                    u0 = E1[e]; u1 = E1[e + 1]; u2 = E1[e + 2]; u3 = E1[e + 3];
                } else {
                    const int oI = kw >> 1;
                    s0 = O0[oI]; s1 = O0[oI + 1]; s2 = O0[oI + 2]; s3 = O0[oI + 3];
                    u0 = O1[oI]; u1 = O1[oI + 1]; u2 = O1[oI + 2]; u3 = O1[oI + 3];
                }
                pk32 t0, t1, t2, t3;
                t0.u = s0; t1.u = s1; t2.u = s2; t3.u = s3;
                va[0][0].hh = __hfma2(k0.hh, t0.hh, va[0][0].hh);
                va[0][1].hh = __hfma2(k1.hh, t1.hh, va[0][1].hh);
                va[0][2].hh = __hfma2(k2.hh, t2.hh, va[0][2].hh);
                va[0][3].hh = __hfma2(k3.hh, t3.hh, va[0][3].hh);
                t0.u = u0; t1.u = u1; t2.u = u2; t3.u = u3;
                va[1][0].hh = __hfma2(k0.hh, t0.hh, va[1][0].hh);
                va[1][1].hh = __hfma2(k1.hh, t1.hh, va[1][1].hh);
                va[1][2].hh = __hfma2(k2.hh, t2.hh, va[1][2].hh);
                va[1][3].hh = __hfma2(k3.hh, t3.hh, va[1][3].hh);
            }
#pragma unroll
            for (int c = 0; c < 2; ++c)
#pragma unroll
                for (int j = 0; j < 4; ++j) {
                    const float2 f = __half22float2(va[c][j].hh);
                    oa[c][2 * j]     += f.x;
                    oa[c][2 * j + 1] += f.y;
                }
        }
#pragma unroll
        for (int c = 0; c < 2; ++c) {
            float* op = out + (size_t)(b * CC + g * CGR + ch0 + c) * HWP
                            + (h0 + r) * WW + 8 * wq;
            *(float4*)&op[0] = make_float4(oa[c][0], oa[c][1], oa[c][2], oa[c][3]);
            *(float4*)&op[4] = make_float4(oa[c][4], oa[c][5], oa[c][6], oa[c][7]);
        }
    }
}

extern "C" void kernel_launch(void* const* d_in, const int* in_sizes, int n_in,
                              void* d_out, int out_size, void* d_ws, size_t ws_size,
                              hipStream_t stream)
{
    const float* x  = (const float*)d_in[0];   // (4,256,56,56)
    const float* rw = (const float*)d_in[1];   // (64,256)
    const float* rb = (const float*)d_in[2];   // (64,)
    const float* sw = (const float*)d_in[3];   // (784,64)
    const float* sb = (const float*)d_in[4];   // (784,)
    float* out  = (float*)d_out;               // (4,256,56,56)

    uint32_t* h2 = (uint32_t*)d_ws;            // (4,32,3136) u32 = 1.6 MB

    gemm1_mfma<<<dim3(HWP / 16, 1, 4), 256, 0, stream>>>(rw, rb, x, h2);
    invol_fused<<<dim3(HH / TH, GG, 4), 256, 0, stream>>>(x, h2, sw, sb, out);
}

// Round 11
// 97.631 us; speedup vs baseline: 1.0577x; 1.0577x over previous
//
#include <hip/hip_runtime.h>
#include <hip/hip_fp16.h>
#include <stdint.h>

#define HH   56
#define WW   56
#define HWP  3136
#define CC   256
#define GG   16
#define CGR  16
#define KT   7
#define KK   49
#define RCP  32            // packed f16 channel-pairs (64 ch)
#define TH   2
#define XROW 32            // u32 per sXh row (64 f16)
#define XPL  260           // u32 per sXh ch-plane (8*32+4)

typedef _Float16 h2_t   __attribute__((ext_vector_type(2)));
typedef __fp16   fp16x2 __attribute__((ext_vector_type(2)));
typedef _Float16 v8h    __attribute__((ext_vector_type(8)));
typedef float    v4f    __attribute__((ext_vector_type(4)));
union pk32 { uint32_t u; h2_t h; __half2 hh; fp16x2 f; };
union frag { uint32_t u[4]; v8h h; };

static __device__ __forceinline__ uint32_t pkrtz(float a, float b) {
    pk32 p; p.f = __builtin_amdgcn_cvt_pkrtz(a, b); return p.u;
}

// pack a 32-wide f32 k-segment into an 8xf16 MFMA A-half-fragment
static __device__ __forceinline__ frag pack_afrag(const float* rowp, int quad) {
    frag a;
    const float4 p0 = *(const float4*)&rowp[quad * 8];
    const float4 p1 = *(const float4*)&rowp[quad * 8 + 4];
    a.u[0] = pkrtz(p0.x, p0.y); a.u[1] = pkrtz(p0.z, p0.w);
    a.u[2] = pkrtz(p1.x, p1.y); a.u[3] = pkrtz(p1.z, p1.w);
    return a;
}

// ---- gemm1 via MFMA: h2[b][cpair][px] planes; px-tile 32, K=256 prefetched ----
__global__ __launch_bounds__(256)
void gemm1_mfma(const float* __restrict__ rw, const float* __restrict__ rb,
                const float* __restrict__ x, uint32_t* __restrict__ h2)
{
    const int b = blockIdx.z, px0 = blockIdx.x * 32;
    const int t = threadIdx.x;
    const int wave = t >> 6, lane = t & 63, quad = lane >> 4, n16 = lane & 15;

    __shared__ __align__(16) uint32_t ldsB[2][8 * 128];   // [buf][q4*128+px*4+jj], 8 KB

    const int px = t & 31;          // staging: 32 px x 8 q4
    const int q4 = t >> 5;
    const float* xb = x + (size_t)b * CC * HWP + px0 + px;

    // prefetch all 4 K-chunks of B (x) into registers
    float r[4][8];
#pragma unroll
    for (int k = 0; k < 4; ++k)
#pragma unroll
        for (int cc = 0; cc < 8; ++cc)
            r[k][cc] = xb[(size_t)(k * 64 + q4 * 8 + cc) * HWP];

    // pack all 4 K-chunks of A (rw, f32 -> f16) up-front
    const float* rwr = rw + (size_t)(wave * 16 + n16) * CC;
    frag af0[4], af1[4];
#pragma unroll
    for (int k = 0; k < 4; ++k) {
        af0[k] = pack_afrag(rwr + k * 64, quad);
        af1[k] = pack_afrag(rwr + k * 64 + 32, quad);
    }

    {   // stage chunk 0
        uint4 w;
        w.x = pkrtz(r[0][0], r[0][1]); w.y = pkrtz(r[0][2], r[0][3]);
        w.z = pkrtz(r[0][4], r[0][5]); w.w = pkrtz(r[0][6], r[0][7]);
        *(uint4*)&ldsB[0][q4 * 128 + px * 4] = w;
    }
    __syncthreads();

    v4f acc[2];
    acc[0] = v4f{0.f,0.f,0.f,0.f}; acc[1] = v4f{0.f,0.f,0.f,0.f};
#pragma unroll
    for (int k = 0; k < 4; ++k) {
        if (k < 3) {    // stage next chunk into other buffer (register source only)
            uint4 w;
            w.x = pkrtz(r[k+1][0], r[k+1][1]); w.y = pkrtz(r[k+1][2], r[k+1][3]);
            w.z = pkrtz(r[k+1][4], r[k+1][5]); w.w = pkrtz(r[k+1][6], r[k+1][7]);
            *(uint4*)&ldsB[(k + 1) & 1][q4 * 128 + px * 4] = w;
        }
        const uint32_t* B = ldsB[k & 1];
#pragma unroll
        for (int nt = 0; nt < 2; ++nt) {
            frag b0, b1;
            *(uint4*)b0.u = *(const uint4*)&B[quad * 128 + (nt * 16 + n16) * 4];
            *(uint4*)b1.u = *(const uint4*)&B[(4 + quad) * 128 + (nt * 16 + n16) * 4];
            acc[nt] = __builtin_amdgcn_mfma_f32_16x16x32_f16(af0[k].h, b0.h, acc[nt], 0, 0, 0);
            acc[nt] = __builtin_amdgcn_mfma_f32_16x16x32_f16(af1[k].h, b1.h, acc[nt], 0, 0, 0);
        }
        __syncthreads();
    }
    uint32_t* hb = h2 + (size_t)b * RCP * HWP + px0;
#pragma unroll
    for (int nt = 0; nt < 2; ++nt)
#pragma unroll
        for (int pr = 0; pr < 2; ++pr) {
            const int m0 = wave * 16 + quad * 4 + 2 * pr;
            hb[(size_t)(wave * 8 + quad * 2 + pr) * HWP + nt * 16 + n16] =
                pkrtz(acc[nt][2 * pr] + rb[m0], acc[nt][2 * pr + 1] + rb[m0 + 1]);
        }
}

// ---- fused MFMA kern-gen + pk-f16 involution (TH=2, 2ch/thread phase C) ----
// LDS: sXh 16.25 KB + U 14 KB (ldsB overlaid with sK f16) = 30.3 KB -> 4 blocks/CU
__global__ __launch_bounds__(256, 4)
void invol_fused(const float* __restrict__ x, const uint32_t* __restrict__ h2,
                 const float* __restrict__ sw, const float* __restrict__ sb,
                 float* __restrict__ out)
{
    const int h0 = blockIdx.x * TH, g = blockIdx.y, b = blockIdx.z;

    __shared__ __align__(16) uint32_t sXh[16 * XPL];      // f16 x, [ch][row][64f16]
    __shared__ __align__(16) uint32_t U[8 * 448];         // ldsB [q4*448+px*4+jj]; later sK f16 [tap*112+px]

    const int t = threadIdx.x;
    const int wave = t >> 6, lane = t & 63, quad = lane >> 4, n16 = lane & 15;

    // A-frags packed from f32 sw (wave-uniform row block, L2/L3-hot)
    const int mt0 = wave * 16 + n16;
    const int mtap = mt0 > 48 ? 48 : mt0;
    const float* swr = sw + (size_t)(g * KK + mtap) * 64;
    const frag a0 = pack_afrag(swr, quad);
    const frag a1 = pack_afrag(swr + 32, quad);

    float bvv[4];
#pragma unroll
    for (int reg = 0; reg < 4; ++reg) {
        const int tp = wave * 16 + quad * 4 + reg;
        bvv[reg] = (tp < KK) ? sb[g * KK + tp] : 0.f;
    }

    // stage h2 -> ldsB in B-frag order (one b128 write per 4-channel gather)
    {
        const uint32_t* hb = h2 + (size_t)b * RCP * HWP + h0 * WW;
#pragma unroll
        for (int k = 0; k < 4; ++k) {
            const int i = t + 256 * k;                  // 896 slots
            if (i < 896) {
                const int px = i % 112, q4 = i / 112;
                uint4 w;
                w.x = hb[(size_t)(q4 * 4 + 0) * HWP + px];
                w.y = hb[(size_t)(q4 * 4 + 1) * HWP + px];
                w.z = hb[(size_t)(q4 * 4 + 2) * HWP + px];
                w.w = hb[(size_t)(q4 * 4 + 3) * HWP + px];
                *(uint4*)&U[q4 * 448 + px * 4] = w;
            }
        }
    }

    // halo zero: f16 cols 0..3 / 60..63 per (ch,row) — one b64 per thread
    {
        const int ch = t >> 4, rr = (t >> 1) & 7, side = t & 1;
        uint2 z; z.x = 0; z.y = 0;
        *(uint2*)&sXh[ch * XPL + rr * XROW + (side ? 30 : 0)] = z;
    }

    // x interior -> f16 (invalid rows write zero)
    {
        const float* xb = x + (size_t)(b * CC + g * CGR) * HWP;
#pragma unroll
        for (int k = 0; k < 7; ++k) {
            const int i = t + 256 * k;                  // 1792 exact
            const int w4 = i % 14, rr = (i / 14) % 8, ch = i / 112;
            const int hh = h0 - 3 + rr;
            float4 v = make_float4(0.f, 0.f, 0.f, 0.f);
            if (hh >= 0 && hh < HH)
                v = *(const float4*)&xb[(size_t)ch * HWP + hh * WW + 4 * w4];
            uint2 p; p.x = pkrtz(v.x, v.y); p.y = pkrtz(v.z, v.w);
            *(uint2*)&sXh[ch * XPL + rr * XROW + 2 + 2 * w4] = p;
        }
    }
    __syncthreads();                                    // barrier 1

    // MFMA: K[49][112] = SW[49][64] @ H[64][112]; B-frag = one b128
    v4f acc[7];
#pragma unroll
    for (int nt = 0; nt < 7; ++nt) acc[nt] = v4f{0.f,0.f,0.f,0.f};
#pragma unroll
    for (int nt = 0; nt < 7; ++nt) {
        const int pxm = (nt * 16 + n16) * 4;
        frag b0, b1;
        *(uint4*)b0.u = *(const uint4*)&U[quad * 448 + pxm];
        *(uint4*)b1.u = *(const uint4*)&U[(4 + quad) * 448 + pxm];
        acc[nt] = __builtin_amdgcn_mfma_f32_16x16x32_f16(a0.h, b0.h, acc[nt], 0, 0, 0);
        acc[nt] = __builtin_amdgcn_mfma_f32_16x16x32_f16(a1.h, b1.h, acc[nt], 0, 0, 0);
    }
    __syncthreads();                                    // barrier 2: ldsB dead

    // epilogue -> sK f16 [tap][112]
    {
        _Float16* sK = (_Float16*)U;
#pragma unroll
        for (int nt = 0; nt < 7; ++nt) {
            const int px = nt * 16 + n16;
#pragma unroll
            for (int reg = 0; reg < 4; ++reg) {
                const int tp = wave * 16 + quad * 4 + reg;
                if (tp < KK) sK[tp * 112 + px] = (_Float16)(acc[nt][reg] + bvv[reg]);
            }
        }
    }
    __syncthreads();                                    // barrier 3

    // phase C: t<112; thread = (ch-pair, r, wq): 2 ch x 8 px outputs
    // kern b128s amortized over 2 channels -> 4.8 LDS-b128/output (was 7.9)
    if (t < 112) {
        const int chp = t & 7, q = t >> 3;              // q 0..13
        const int r = q & 1, wq = q >> 1;               // wq 0..6
        const int ch0 = 2 * chp;
        const uint32_t* xp0 = &sXh[ch0 * XPL + 4 * wq];
        const uint32_t* xp1 = &sXh[(ch0 + 1) * XPL + 4 * wq];
        float oa[2][8];
#pragma unroll
        for (int c = 0; c < 2; ++c)
#pragma unroll
            for (int j = 0; j < 8; ++j) oa[c][j] = 0.f;

#pragma unroll
        for (int kh = 0; kh < KT; ++kh) {
            const int rr = r + kh;
            uint32_t E0[8], E1[8], O0[7], O1[7];
            *(uint4*)&E0[0] = *(const uint4*)&xp0[rr * XROW];
            *(uint4*)&E0[4] = *(const uint4*)&xp0[rr * XROW + 4];
            *(uint4*)&E1[0] = *(const uint4*)&xp1[rr * XROW];
            *(uint4*)&E1[4] = *(const uint4*)&xp1[rr * XROW + 4];
#pragma unroll
            for (int j = 0; j < 7; ++j) {
                O0[j] = __builtin_amdgcn_alignbit(E0[j + 1], E0[j], 16);
                O1[j] = __builtin_amdgcn_alignbit(E1[j + 1], E1[j], 16);
            }
            pk32 va[2][4];
#pragma unroll
            for (int c = 0; c < 2; ++c)
#pragma unroll
                for (int j = 0; j < 4; ++j) va[c][j].u = 0;

            const uint32_t* kq = &U[(kh * KT) * 56 + r * 28 + 4 * wq];
#pragma unroll
            for (int kw = 0; kw < KT; ++kw) {
                const uint4 kk = *(const uint4*)&kq[kw * 56];
                pk32 k0, k1, k2, k3; k0.u = kk.x; k1.u = kk.y; k2.u = kk.z; k3.u = kk.w;
                pk32 s0, s1, s2, s3;
                if (kw & 1) {
                    const int e = (kw + 1) >> 1;
                    s0.u = E0[e]; s1.u = E0[e + 1]; s2.u = E0[e + 2]; s3.u = E0[e + 3];
                } else {
                    const int oI = kw >> 1;
                    s0.u = O0[oI]; s1.u = O0[oI + 1]; s2.u = O0[oI + 2]; s3.u = O0[oI + 3];
                }
                va[0][0].hh = __hfma2(k0.hh, s0.hh, va[0][0].hh);
                va[0][1].hh = __hfma2(k1.hh, s1.hh, va[0][1].hh);
                va[0][2].hh = __hfma2(k2.hh, s2.hh, va[0][2].hh);
                va[0][3].hh = __hfma2(k3.hh, s3.hh, va[0][3].hh);
                if (kw & 1) {
                    const int e = (kw + 1) >> 1;
                    s0.u = E1[e]; s1.u = E1[e + 1]; s2.u = E1[e + 2]; s3.u = E1[e + 3];
                } else {
                    const int oI = kw >> 1;
                    s0.u = O1[oI]; s1.u = O1[oI + 1]; s2.u = O1[oI + 2]; s3.u = O1[oI + 3];
                }
                va[1][0].hh = __hfma2(k0.hh, s0.hh, va[1][0].hh);
                va[1][1].hh = __hfma2(k1.hh, s1.hh, va[1][1].hh);
                va[1][2].hh = __hfma2(k2.hh, s2.hh, va[1][2].hh);
                va[1][3].hh = __hfma2(k3.hh, s3.hh, va[1][3].hh);
            }
#pragma unroll
            for (int c = 0; c < 2; ++c)
#pragma unroll
                for (int j = 0; j < 4; ++j) {
                    const float2 f = __half22float2(va[c][j].hh);
                    oa[c][2 * j]     += f.x;
                    oa[c][2 * j + 1] += f.y;
                }
        }
#pragma unroll
        for (int c = 0; c < 2; ++c) {
            float* op = out + (size_t)(b * CC + g * CGR + ch0 + c) * HWP
                            + (h0 + r) * WW + 8 * wq;
            *(float4*)&op[0] = make_float4(oa[c][0], oa[c][1], oa[c][2], oa[c][3]);
            *(float4*)&op[4] = make_float4(oa[c][4], oa[c][5], oa[c][6], oa[c][7]);
        }
    }
}

extern "C" void kernel_launch(void* const* d_in, const int* in_sizes, int n_in,
                              void* d_out, int out_size, void* d_ws, size_t ws_size,
                              hipStream_t stream)
{
    const float* x  = (const float*)d_in[0];   // (4,256,56,56)
    const float* rw = (const float*)d_in[1];   // (64,256)
    const float* rb = (const float*)d_in[2];   // (64,)
    const float* sw = (const float*)d_in[3];   // (784,64)
    const float* sb = (const float*)d_in[4];   // (784,)
    float* out  = (float*)d_out;               // (4,256,56,56)

    uint32_t* h2 = (uint32_t*)d_ws;            // (4,32,3136) u32 = 1.6 MB

    gemm1_mfma<<<dim3(HWP / 32, 1, 4), 256, 0, stream>>>(rw, rb, x, h2);
    invol_fused<<<dim3(HH / TH, GG, 4), 256, 0, stream>>>(x, h2, sw, sb, out);
}